// Round 3
// baseline (27.229 us; speedup 1.0000x reference)
//
#include <hip/hip_runtime.h>

// Problem constants (match reference)
#define B_TOTAL 16777216
#define NSTEPS 64

#define GRID 2048
#define BLOCK 256
#define ITERS 8  // GRID*BLOCK*ITERS*4 == B_TOTAL exactly

// Fully-fused, barrier-free streaming kernel.
//  - EVERY wave computes surv = prod(1 - sigmoid(raw_gammas)) itself:
//    256 B uniform read (L1/L2-hot), 1 __expf, 6-step butterfly product.
//    No LDS, no __syncthreads -> waves start streaming immediately.
//  - Block 0 / first wave also writes gammas to the output tail.
//  - Streaming: 8 independent float4 loads issued up front (128 B/lane in
//    flight), then 8 fused cos*surv+oms stores drain in load order.
__global__ void __launch_bounds__(BLOCK) qm_fused_kernel(
        const float* __restrict__ thetas,
        const float* __restrict__ raw_gammas,
        float* __restrict__ out_expvals,
        float* __restrict__ out_gammas) {
    const int lane = threadIdx.x & 63;

    // Per-wave survival product (uniform result across all 64 lanes)
    float rg = raw_gammas[lane];
    float g = 1.0f / (1.0f + __expf(-rg));
    if (blockIdx.x == 0 && threadIdx.x < 64) {
        out_gammas[threadIdx.x] = g;
    }
    float v = 1.0f - g;
    #pragma unroll
    for (int off = 32; off > 0; off >>= 1) {
        v *= __shfl_xor(v, off, 64);
    }
    const float surv = v;
    const float oms = 1.0f - surv;

    const float4* __restrict__ t4 = reinterpret_cast<const float4*>(thetas);
    float4* __restrict__ o4 = reinterpret_cast<float4*>(out_expvals);

    const int base = blockIdx.x * BLOCK + threadIdx.x;
    const int stride = GRID * BLOCK;

    // Issue all 8 independent loads first for maximum MLP.
    float4 t[ITERS];
    #pragma unroll
    for (int k = 0; k < ITERS; ++k) {
        t[k] = t4[base + k * stride];
    }
    // Compute + store, draining in load order.
    #pragma unroll
    for (int k = 0; k < ITERS; ++k) {
        float4 r;
        r.x = fmaf(__cosf(t[k].x), surv, oms);
        r.y = fmaf(__cosf(t[k].y), surv, oms);
        r.z = fmaf(__cosf(t[k].z), surv, oms);
        r.w = fmaf(__cosf(t[k].w), surv, oms);
        o4[base + k * stride] = r;
    }
}

extern "C" void kernel_launch(void* const* d_in, const int* in_sizes, int n_in,
                              void* d_out, int out_size, void* d_ws, size_t ws_size,
                              hipStream_t stream) {
    const float* thetas = (const float*)d_in[0];
    // d_in[1] = phis: unused (RZ does not change <Z>)
    const float* raw_gammas = (const float*)d_in[2];

    float* out_expvals = (float*)d_out;              // [B_TOTAL]
    float* out_gammas = (float*)d_out + B_TOTAL;     // [NSTEPS]

    qm_fused_kernel<<<GRID, BLOCK, 0, stream>>>(thetas, raw_gammas,
                                                out_expvals, out_gammas);
}